// Round 1
// baseline (257.006 us; speedup 1.0000x reference)
//
#include <hip/hip_runtime.h>
#include <math.h>

#define NB 8
#define NS 2048
#define NF 32
#define ND 256
#define NTOK (NB * NS)

// One wave (64 lanes) per token. lane l owns d = 4l..4l+3 (float4 everywhere).
// z[32][4] kept in registers across the softmax boundary (statically indexed,
// fully unrolled). All reductions are wave-level shfl_xor butterflies.
__global__ __launch_bounds__(256, 2) void vsn_kernel(
    const float* __restrict__ x,     // [NTOK, NF]
    const float* __restrict__ W,     // [NF, ND]
    const float* __restrict__ bias,  // [NF, ND]
    const float* __restrict__ ln1g,  // [ND]
    const float* __restrict__ ln1b,  // [ND]
    const float* __restrict__ scw,   // [ND]
    const float* __restrict__ scb,   // [1]
    const float* __restrict__ outg,  // [ND]
    const float* __restrict__ outb,  // [ND]
    float* __restrict__ out,         // [NTOK, ND]
    float* __restrict__ wout)        // [NTOK, NF]
{
    const int lane = threadIdx.x & 63;
    const int wid  = threadIdx.x >> 6;
    const int tok  = (blockIdx.x << 2) | wid;   // grid = NTOK/4 exactly
    const int d0   = lane << 2;

    // x row broadcast source: lane l holds x[tok][l&31]
    const float xv = x[tok * NF + (lane & 31)];

    const float4 g4  = *(const float4*)(ln1g + d0);
    const float4 bb4 = *(const float4*)(ln1b + d0);
    const float4 sw4 = *(const float4*)(scw + d0);
    const float  sbv = scb[0];

    float z[NF][4];
    float myscore = 0.0f;

    constexpr float inv_d = 1.0f / 256.0f;
    constexpr float inv_sqrt2 = 0.70710678118654752440f;

#pragma unroll
    for (int f = 0; f < NF; ++f) {
        const float xf = __shfl(xv, f);  // constant src lane -> readlane/SGPR
        const float4 w4 = *(const float4*)(W + f * ND + d0);
        const float4 c4 = *(const float4*)(bias + f * ND + d0);
        const float z0 = fmaf(xf, w4.x, c4.x);
        const float z1 = fmaf(xf, w4.y, c4.y);
        const float z2 = fmaf(xf, w4.z, c4.z);
        const float z3 = fmaf(xf, w4.w, c4.w);
        z[f][0] = z0; z[f][1] = z1; z[f][2] = z2; z[f][3] = z3;

        float s = (z0 + z1) + (z2 + z3);
        float q = fmaf(z0, z0, fmaf(z1, z1, fmaf(z2, z2, z3 * z3)));
#pragma unroll
        for (int m = 32; m >= 1; m >>= 1) {
            s += __shfl_xor(s, m);
            q += __shfl_xor(q, m);
        }
        const float mu  = s * inv_d;
        const float var = fmaf(-mu, mu, q * inv_d);
        const float rs  = rsqrtf(var + 1e-5f);

        // n = LN(z) with ln1 affine; h = exact gelu(n); dot with score_w
        const float n0 = fmaf((z0 - mu) * rs, g4.x, bb4.x);
        const float n1 = fmaf((z1 - mu) * rs, g4.y, bb4.y);
        const float n2 = fmaf((z2 - mu) * rs, g4.z, bb4.z);
        const float n3 = fmaf((z3 - mu) * rs, g4.w, bb4.w);
        const float h0 = 0.5f * n0 * (1.0f + erff(n0 * inv_sqrt2));
        const float h1 = 0.5f * n1 * (1.0f + erff(n1 * inv_sqrt2));
        const float h2 = 0.5f * n2 * (1.0f + erff(n2 * inv_sqrt2));
        const float h3 = 0.5f * n3 * (1.0f + erff(n3 * inv_sqrt2));

        float dp = fmaf(h0, sw4.x, fmaf(h1, sw4.y, fmaf(h2, sw4.z, h3 * sw4.w)));
#pragma unroll
        for (int m = 32; m >= 1; m >>= 1) dp += __shfl_xor(dp, m);
        if (lane == f) myscore = dp + sbv;  // lane f parks score_f
    }

    // softmax over f: scores live one-per-lane in lanes 0..31
    const float sc = (lane < NF) ? myscore : -3.0e38f;
    float mx = sc;
#pragma unroll
    for (int m = 32; m >= 1; m >>= 1) mx = fmaxf(mx, __shfl_xor(mx, m));
    const float ev = (lane < NF) ? __expf(sc - mx) : 0.0f;
    float es = ev;
#pragma unroll
    for (int m = 32; m >= 1; m >>= 1) es += __shfl_xor(es, m);
    const float wt = ev / es;

    // pass 2: selected[d] = sum_f z[f][d] * wt[f]
    float s0 = 0.f, s1 = 0.f, s2 = 0.f, s3 = 0.f;
#pragma unroll
    for (int f = 0; f < NF; ++f) {
        const float wf = __shfl(wt, f);
        s0 = fmaf(z[f][0], wf, s0);
        s1 = fmaf(z[f][1], wf, s1);
        s2 = fmaf(z[f][2], wf, s2);
        s3 = fmaf(z[f][3], wf, s3);
    }

    // final LN over selected
    float s = (s0 + s1) + (s2 + s3);
    float q = fmaf(s0, s0, fmaf(s1, s1, fmaf(s2, s2, s3 * s3)));
#pragma unroll
    for (int m = 32; m >= 1; m >>= 1) {
        s += __shfl_xor(s, m);
        q += __shfl_xor(q, m);
    }
    const float mu  = s * inv_d;
    const float var = fmaf(-mu, mu, q * inv_d);
    const float rs  = rsqrtf(var + 1e-5f);

    const float4 og4 = *(const float4*)(outg + d0);
    const float4 ob4 = *(const float4*)(outb + d0);
    float4 o;
    o.x = fmaf((s0 - mu) * rs, og4.x, ob4.x);
    o.y = fmaf((s1 - mu) * rs, og4.y, ob4.y);
    o.z = fmaf((s2 - mu) * rs, og4.z, ob4.z);
    o.w = fmaf((s3 - mu) * rs, og4.w, ob4.w);
    *(float4*)(out + tok * ND + d0) = o;

    if (lane < NF) wout[tok * NF + lane] = wt;
}

extern "C" void kernel_launch(void* const* d_in, const int* in_sizes, int n_in,
                              void* d_out, int out_size, void* d_ws, size_t ws_size,
                              hipStream_t stream) {
    const float* x    = (const float*)d_in[0];
    const float* W    = (const float*)d_in[1];
    const float* bias = (const float*)d_in[2];
    const float* ln1g = (const float*)d_in[3];
    const float* ln1b = (const float*)d_in[4];
    const float* scw  = (const float*)d_in[5];
    const float* scb  = (const float*)d_in[6];
    const float* outg = (const float*)d_in[7];
    const float* outb = (const float*)d_in[8];

    float* out  = (float*)d_out;                       // [NTOK, ND]
    float* wout = out + (size_t)NTOK * ND;             // [NTOK, NF]

    dim3 grid(NTOK / 4), block(256);
    hipLaunchKernelGGL(vsn_kernel, grid, block, 0, stream,
                       x, W, bias, ln1g, ln1b, scw, scb, outg, outb, out, wout);
}

// Round 2
// 109.112 us; speedup vs baseline: 2.3554x; 2.3554x over previous
//
#include <hip/hip_runtime.h>
#include <math.h>

#define NB 8
#define NS 2048
#define NF 32
#define ND 256
#define NTOK (NB * NS)

// ---------- DPP wave-sum (64 lanes, result lands in lane 63) ----------
template <int CTRL, int RM>
__device__ __forceinline__ float dpp_step(float v) {
    int t = __builtin_amdgcn_update_dpp(0, __float_as_int(v), CTRL, RM, 0xf, true);
    return v + __int_as_float(t);
}
__device__ __forceinline__ float wave_sum63(float v) {
    v = dpp_step<0x111, 0xf>(v);  // row_shr:1
    v = dpp_step<0x112, 0xf>(v);  // row_shr:2
    v = dpp_step<0x114, 0xf>(v);  // row_shr:4
    v = dpp_step<0x118, 0xf>(v);  // row_shr:8
    v = dpp_step<0x142, 0xa>(v);  // row_bcast:15 -> rows 1,3
    v = dpp_step<0x143, 0xc>(v);  // row_bcast:31 -> rows 2,3
    return v;                     // lane 63 holds the total
}
__device__ __forceinline__ float wave_sum_bcast(float v) {
    return __int_as_float(__builtin_amdgcn_readlane(__float_as_int(wave_sum63(v)), 63));
}

// ---------- branchless erf, A&S 7.1.26, |err| <= 1.5e-7 ----------
__device__ __forceinline__ float erf_fast_abs(float a) {  // a = |u|
    const float t = __builtin_amdgcn_rcpf(fmaf(0.3275911f, a, 1.0f));
    const float poly = t * fmaf(t, fmaf(t, fmaf(t, fmaf(t, 1.061405429f, -1.453152027f),
                                                1.421413741f), -0.284496736f), 0.254829592f);
    const float e = __expf(-a * a);
    return fmaf(-poly, e, 1.0f);
}

// gelu(n)*scw where u = n/sqrt2 and swc = scw/sqrt2 pre-folded:
// gelu(n) = 0.5*n*(1+erf(u)) = (1/sqrt2)*u*(1+erf(u))
__device__ __forceinline__ float gelu_dot(float u, float swc) {
    const float er = copysignf(erf_fast_abs(fabsf(u)), u);
    return u * (1.0f + er) * swc;
}

// ---------- per-f row statistics of W,b (token-independent) ----------
__global__ void vsn_stats(const float* __restrict__ W, const float* __restrict__ bias,
                          float* __restrict__ stats) {
    const int f = blockIdx.x;       // 32 blocks
    const int lane = threadIdx.x;   // 64 threads
    const float4 w4 = *(const float4*)(W + f * ND + (lane << 2));
    const float4 b4 = *(const float4*)(bias + f * ND + (lane << 2));
    float sw  = (w4.x + w4.y) + (w4.z + w4.w);
    float sb  = (b4.x + b4.y) + (b4.z + b4.w);
    float sww = fmaf(w4.x, w4.x, fmaf(w4.y, w4.y, fmaf(w4.z, w4.z, w4.w * w4.w)));
    float swb = fmaf(w4.x, b4.x, fmaf(w4.y, b4.y, fmaf(w4.z, b4.z, w4.w * b4.w)));
    float sbb = fmaf(b4.x, b4.x, fmaf(b4.y, b4.y, fmaf(b4.z, b4.z, b4.w * b4.w)));
#pragma unroll
    for (int m = 32; m >= 1; m >>= 1) {
        sw += __shfl_xor(sw, m);  sb += __shfl_xor(sb, m);
        sww += __shfl_xor(sww, m); swb += __shfl_xor(swb, m); sbb += __shfl_xor(sbb, m);
    }
    if (lane == 0) {
        const float inv_d = 1.0f / ND;
        stats[f]        = sw * inv_d;
        stats[32 + f]   = sb * inv_d;
        stats[64 + f]   = sww * inv_d;
        stats[96 + f]   = swb * inv_d;
        stats[128 + f]  = sbb * inv_d;
    }
}

// ---------- main kernel: one wave per token, lane l owns d=4l..4l+3 ----------
__global__ __launch_bounds__(256, 2) void vsn_kernel(
    const float* __restrict__ x,      // [NTOK, NF]
    const float* __restrict__ W,      // [NF, ND]
    const float* __restrict__ bias,   // [NF, ND]
    const float* __restrict__ stats,  // [5, NF] from vsn_stats
    const float* __restrict__ ln1g,
    const float* __restrict__ ln1b,
    const float* __restrict__ scw,
    const float* __restrict__ scb,
    const float* __restrict__ outg,
    const float* __restrict__ outb,
    float* __restrict__ out,          // [NTOK, ND]
    float* __restrict__ wout)         // [NTOK, NF]
{
    const int lane = threadIdx.x & 63;
    const int wid  = threadIdx.x >> 6;
    const int tok  = (blockIdx.x << 2) | wid;
    const int d0   = lane << 2;
    const int fl   = lane & 31;

    constexpr float inv_d = 1.0f / 256.0f;
    constexpr float c = 0.70710678118654752440f;  // 1/sqrt(2)

    const float xv = x[tok * NF + fl];

    // closed-form LN1 stats for f = fl (no cross-lane reduction needed)
    const float mu_l  = fmaf(xv, stats[fl], stats[32 + fl]);
    const float ez2   = fmaf(xv * xv, stats[64 + fl],
                             fmaf(xv + xv, stats[96 + fl], stats[128 + fl]));
    const float var_l = fmaf(-mu_l, mu_l, ez2);
    const float rsc_l = rsqrtf(var_l + 1e-5f) * c;

    const float4 g4 = *(const float4*)(ln1g + d0);
    float4 bc4 = *(const float4*)(ln1b + d0);
    bc4.x *= c; bc4.y *= c; bc4.z *= c; bc4.w *= c;
    float4 swc4 = *(const float4*)(scw + d0);
    swc4.x *= c; swc4.y *= c; swc4.z *= c; swc4.w *= c;
    const float sbv = scb[0];

    float z[NF][4];
    float myscore = 0.0f;

#pragma unroll
    for (int f = 0; f < NF; ++f) {
        const float xf  = __shfl(xv, f);
        const float mu  = __shfl(mu_l, f);
        const float rsc = __shfl(rsc_l, f);
        const float4 w4 = *(const float4*)(W + f * ND + d0);
        const float4 c4 = *(const float4*)(bias + f * ND + d0);
        const float z0 = fmaf(xf, w4.x, c4.x);
        const float z1 = fmaf(xf, w4.y, c4.y);
        const float z2 = fmaf(xf, w4.z, c4.z);
        const float z3 = fmaf(xf, w4.w, c4.w);
        z[f][0] = z0; z[f][1] = z1; z[f][2] = z2; z[f][3] = z3;

        // u = LN(z)/sqrt2 with affine folded: u = (z-mu)*rsc*g + b*c
        const float u0 = fmaf((z0 - mu) * rsc, g4.x, bc4.x);
        const float u1 = fmaf((z1 - mu) * rsc, g4.y, bc4.y);
        const float u2 = fmaf((z2 - mu) * rsc, g4.z, bc4.z);
        const float u3 = fmaf((z3 - mu) * rsc, g4.w, bc4.w);

        float dp = gelu_dot(u0, swc4.x) + gelu_dot(u1, swc4.y)
                 + gelu_dot(u2, swc4.z) + gelu_dot(u3, swc4.w);
        dp = wave_sum63(dp);
        const float dps = __int_as_float(__builtin_amdgcn_readlane(__float_as_int(dp), 63));
        if (lane == f) myscore = dps + sbv;
    }

    // softmax over f (scores in lanes 0..31)
    const float sc = (lane < NF) ? myscore : -3.0e38f;
    float mx = sc;
#pragma unroll
    for (int m = 32; m >= 1; m >>= 1) mx = fmaxf(mx, __shfl_xor(mx, m));
    const float ev = (lane < NF) ? __expf(sc - mx) : 0.0f;
    float es = ev;
#pragma unroll
    for (int m = 32; m >= 1; m >>= 1) es += __shfl_xor(es, m);
    const float wt = ev / es;

    // pass 2: selected[d] = sum_f z[f][d] * wt[f]
    float s0 = 0.f, s1 = 0.f, s2 = 0.f, s3 = 0.f;
#pragma unroll
    for (int f = 0; f < NF; ++f) {
        const float wf = __shfl(wt, f);
        s0 = fmaf(z[f][0], wf, s0);
        s1 = fmaf(z[f][1], wf, s1);
        s2 = fmaf(z[f][2], wf, s2);
        s3 = fmaf(z[f][3], wf, s3);
    }

    // final LN over selected (DPP reductions)
    const float s = wave_sum_bcast((s0 + s1) + (s2 + s3));
    const float q = wave_sum_bcast(fmaf(s0, s0, fmaf(s1, s1, fmaf(s2, s2, s3 * s3))));
    const float mu  = s * inv_d;
    const float var = fmaf(-mu, mu, q * inv_d);
    const float rs  = rsqrtf(var + 1e-5f);

    const float4 og4 = *(const float4*)(outg + d0);
    const float4 ob4 = *(const float4*)(outb + d0);
    float4 o;
    o.x = fmaf((s0 - mu) * rs, og4.x, ob4.x);
    o.y = fmaf((s1 - mu) * rs, og4.y, ob4.y);
    o.z = fmaf((s2 - mu) * rs, og4.z, ob4.z);
    o.w = fmaf((s3 - mu) * rs, og4.w, ob4.w);
    *(float4*)(out + tok * ND + d0) = o;

    if (lane < NF) wout[tok * NF + lane] = wt;
}

extern "C" void kernel_launch(void* const* d_in, const int* in_sizes, int n_in,
                              void* d_out, int out_size, void* d_ws, size_t ws_size,
                              hipStream_t stream) {
    const float* x    = (const float*)d_in[0];
    const float* W    = (const float*)d_in[1];
    const float* bias = (const float*)d_in[2];
    const float* ln1g = (const float*)d_in[3];
    const float* ln1b = (const float*)d_in[4];
    const float* scw  = (const float*)d_in[5];
    const float* scb  = (const float*)d_in[6];
    const float* outg = (const float*)d_in[7];
    const float* outb = (const float*)d_in[8];

    float* stats = (float*)d_ws;                 // 5*32 floats
    float* out   = (float*)d_out;                // [NTOK, ND]
    float* wout  = out + (size_t)NTOK * ND;      // [NTOK, NF]

    hipLaunchKernelGGL(vsn_stats, dim3(NF), dim3(64), 0, stream, W, bias, stats);
    hipLaunchKernelGGL(vsn_kernel, dim3(NTOK / 4), dim3(256), 0, stream,
                       x, W, bias, stats, ln1g, ln1b, scw, scb, outg, outb, out, wout);
}